// Round 1
// baseline (1102.045 us; speedup 1.0000x reference)
//
#include <hip/hip_runtime.h>
#include <math.h>

namespace {

constexpr int Bb = 16;
constexpr int Ll = 1024;
constexpr int Dd = 512;     // H*DK = H*DV = 512 flattened channel dim
constexpr int TOPK = 6;

// ---------------------------------------------------------------------------
// C[M,N] = A[M,K] @ B[K,N], fp32 row-major. 64x64 tile, BK=16, 256 thr, 4x4/thr.
// ---------------------------------------------------------------------------
__global__ __launch_bounds__(256) void gemm_nn(
    const float* __restrict__ A, const float* __restrict__ B,
    float* __restrict__ C, int M, int N, int K)
{
  __shared__ float As[64][17];   // +1 pad: column reads -> 2-way (free)
  __shared__ float Bs[16][65];
  const int tid = threadIdx.x;
  const int bx = blockIdx.x;     // N tile
  const int by = blockIdx.y;     // M tile
  const int tr = tid >> 4, tc = tid & 15;
  const int lr = tid >> 2;              // 0..63 (A tile row)
  const int lc = (tid & 3) << 2;        // 0,4,8,12 (A tile col)
  const int br = tid >> 4;              // 0..15 (B tile row)
  const int bc = (tid & 15) << 2;       // 0..60 (B tile col)
  float acc[4][4] = {};
  for (int k0 = 0; k0 < K; k0 += 16) {
    float4 av = *reinterpret_cast<const float4*>(&A[(size_t)(by * 64 + lr) * K + k0 + lc]);
    As[lr][lc + 0] = av.x; As[lr][lc + 1] = av.y; As[lr][lc + 2] = av.z; As[lr][lc + 3] = av.w;
    float4 bv = *reinterpret_cast<const float4*>(&B[(size_t)(k0 + br) * N + bx * 64 + bc]);
    Bs[br][bc + 0] = bv.x; Bs[br][bc + 1] = bv.y; Bs[br][bc + 2] = bv.z; Bs[br][bc + 3] = bv.w;
    __syncthreads();
#pragma unroll
    for (int kk = 0; kk < 16; ++kk) {
      float a[4], b[4];
#pragma unroll
      for (int i = 0; i < 4; ++i) a[i] = As[tr * 4 + i][kk];
#pragma unroll
      for (int j = 0; j < 4; ++j) b[j] = Bs[kk][tc * 4 + j];
#pragma unroll
      for (int i = 0; i < 4; ++i)
#pragma unroll
        for (int j = 0; j < 4; ++j) acc[i][j] = fmaf(a[i], b[j], acc[i][j]);
    }
    __syncthreads();
  }
  const int row0 = by * 64 + tr * 4, col0 = bx * 64 + tc * 4;
#pragma unroll
  for (int i = 0; i < 4; ++i) {
    float4 o = make_float4(acc[i][0], acc[i][1], acc[i][2], acc[i][3]);
    *reinterpret_cast<float4*>(&C[(size_t)(row0 + i) * N + col0]) = o;
  }
}

// ---------------------------------------------------------------------------
// Correlation with fused diagonal reduction:
//   mean_value[b][l] += sum over tile of q_s[b][t]·k_s[b][s] where (t-s)%L == l
// One block = 64x64 tile of the [1024x1024] Gram matrix for batch b.
// ---------------------------------------------------------------------------
__global__ __launch_bounds__(256) void corr_diag(
    const float* __restrict__ qs, const float* __restrict__ ks,
    float* __restrict__ mean_value)
{
  __shared__ float As[64][17];
  __shared__ float Bs[16][65];
  __shared__ float bins[1024];
  const int b = blockIdx.z;
  const float* A  = qs + (size_t)b * Ll * Dd;
  const float* Bk = ks + (size_t)b * Ll * Dd;
  const int tid = threadIdx.x;
  const int bx = blockIdx.x;   // s tile
  const int by = blockIdx.y;   // t tile
  const int tr = tid >> 4, tc = tid & 15;
  const int lr = tid >> 2;
  const int lc = (tid & 3) << 2;
#pragma unroll
  for (int i = 0; i < 4; ++i) bins[tid * 4 + i] = 0.f;
  float acc[4][4] = {};
  for (int k0 = 0; k0 < Dd; k0 += 16) {
    float4 av = *reinterpret_cast<const float4*>(&A[(size_t)(by * 64 + lr) * Dd + k0 + lc]);
    As[lr][lc + 0] = av.x; As[lr][lc + 1] = av.y; As[lr][lc + 2] = av.z; As[lr][lc + 3] = av.w;
    // k tile loaded [s][k], stored transposed into Bs[k][s]
    float4 bv = *reinterpret_cast<const float4*>(&Bk[(size_t)(bx * 64 + lr) * Dd + k0 + lc]);
    Bs[lc + 0][lr] = bv.x; Bs[lc + 1][lr] = bv.y; Bs[lc + 2][lr] = bv.z; Bs[lc + 3][lr] = bv.w;
    __syncthreads();
#pragma unroll
    for (int kk = 0; kk < 16; ++kk) {
      float a[4], bb[4];
#pragma unroll
      for (int i = 0; i < 4; ++i) a[i] = As[tr * 4 + i][kk];
#pragma unroll
      for (int j = 0; j < 4; ++j) bb[j] = Bs[kk][tc * 4 + j];
#pragma unroll
      for (int i = 0; i < 4; ++i)
#pragma unroll
        for (int j = 0; j < 4; ++j) acc[i][j] = fmaf(a[i], bb[j], acc[i][j]);
    }
    __syncthreads();
  }
  const int t0 = by * 64 + tr * 4, s0 = bx * 64 + tc * 4;
#pragma unroll
  for (int i = 0; i < 4; ++i)
#pragma unroll
    for (int j = 0; j < 4; ++j) {
      int l = (t0 + i - (s0 + j)) & (Ll - 1);
      atomicAdd(&bins[l], acc[i][j]);
    }
  __syncthreads();
  // this tile touches exactly 127 diagonals: l = (by*64 - bx*64 + d) & 1023, d in [-63,63]
  if (tid < 127) {
    int base = by * 64 - bx * 64;
    int l = (base + tid - 63) & (Ll - 1);
    atomicAdd(&mean_value[b * Ll + l], bins[l]);
  }
}

__global__ void zero_mv(float* __restrict__ mv)
{
  int i = blockIdx.x * 256 + threadIdx.x;
  if (i < Bb * Ll) mv[i] = 0.f;
}

// ---------------------------------------------------------------------------
// Top-6 of batch-mean correlation + per-batch softmax over selected lags.
// Single block, 1024 threads.
// ---------------------------------------------------------------------------
__global__ __launch_bounds__(1024) void topk_softmax(
    const float* __restrict__ mean_value,
    int* __restrict__ idx_out, float* __restrict__ w_out)
{
  __shared__ float vals[1024];
  __shared__ int   inds[1024];
  __shared__ float bm[1024];
  __shared__ int   topi[TOPK];
  const int t = threadIdx.x;
  float s = 0.f;
  for (int b = 0; b < Bb; ++b) s += mean_value[b * Ll + t];
  bm[t] = s;   // unnormalized batch mean: ranking-equivalent
  __syncthreads();
  for (int k = 0; k < TOPK; ++k) {
    bool taken = false;
    for (int j = 0; j < k; ++j) taken |= (topi[j] == t);
    vals[t] = taken ? -INFINITY : bm[t];
    inds[t] = t;
    __syncthreads();
    for (int stride = 512; stride > 0; stride >>= 1) {
      if (t < stride) {
        if (vals[t + stride] > vals[t]) { vals[t] = vals[t + stride]; inds[t] = inds[t + stride]; }
      }
      __syncthreads();
    }
    if (t == 0) topi[k] = inds[0];
    __syncthreads();
  }
  if (t < TOPK) idx_out[t] = topi[t];
  if (t < Bb) {
    float wv[TOPK], mx = -INFINITY;
#pragma unroll
    for (int k = 0; k < TOPK; ++k) {
      wv[k] = mean_value[t * Ll + topi[k]] * (1.f / 512.f);  // exact (1/(H*E)) scale before softmax
      mx = fmaxf(mx, wv[k]);
    }
    float sum = 0.f;
#pragma unroll
    for (int k = 0; k < TOPK; ++k) { wv[k] = expf(wv[k] - mx); sum += wv[k]; }
#pragma unroll
    for (int k = 0; k < TOPK; ++k) w_out[t * TOPK + k] = wv[k] / sum;
  }
}

// ---------------------------------------------------------------------------
// context[b][l][c] = sum_k w[b][k] * v_s[b][(l+idx_k)%L][c]
// ---------------------------------------------------------------------------
__global__ __launch_bounds__(128) void aggregate(
    const float* __restrict__ vs, const float* __restrict__ w,
    const int* __restrict__ idx, float* __restrict__ ctx)
{
  const int l = blockIdx.x, b = blockIdx.y;
  __shared__ float ww[TOPK];
  __shared__ int   ii[TOPK];
  if (threadIdx.x < TOPK) { ww[threadIdx.x] = w[b * TOPK + threadIdx.x]; ii[threadIdx.x] = idx[threadIdx.x]; }
  __syncthreads();
  const int c = threadIdx.x << 2;
  const float* vb = vs + (size_t)b * Ll * Dd;
  float4 acc = make_float4(0.f, 0.f, 0.f, 0.f);
#pragma unroll
  for (int k = 0; k < TOPK; ++k) {
    const float4 vv = *reinterpret_cast<const float4*>(&vb[(size_t)((l + ii[k]) & (Ll - 1)) * Dd + c]);
    const float wk = ww[k];
    acc.x = fmaf(wk, vv.x, acc.x);
    acc.y = fmaf(wk, vv.y, acc.y);
    acc.z = fmaf(wk, vv.z, acc.z);
    acc.w = fmaf(wk, vv.w, acc.w);
  }
  *reinterpret_cast<float4*>(&ctx[((size_t)b * Ll + l) * Dd + c]) = acc;
}

}  // namespace

extern "C" void kernel_launch(void* const* d_in, const int* in_sizes, int n_in,
                              void* d_out, int out_size, void* d_ws, size_t ws_size,
                              hipStream_t stream)
{
  const float* Q   = (const float*)d_in[0];
  const float* K   = (const float*)d_in[1];
  const float* V   = (const float*)d_in[2];
  // d_in[3] attn_mask: ignored by AutoCorrelation
  const float* WQ  = (const float*)d_in[4];
  const float* WK  = (const float*)d_in[5];
  const float* WV  = (const float*)d_in[6];
  const float* Wfc = (const float*)d_in[7];
  float* out = (float*)d_out;

  float* ws = (float*)d_ws;
  const size_t BLD = (size_t)Bb * Ll * Dd;       // 8,388,608 floats
  float* qs  = ws;
  float* ks_ = ws + BLD;
  float* vs  = ws + 2 * BLD;
  float* mv  = ws + 3 * BLD;                     // [16][1024]
  float* w   = mv + Bb * Ll;                     // [16][6]
  int*   idx = (int*)(w + 128);                  // [6]
  float* ctx = qs;                               // reuse: q_s dead after corr_diag

  const dim3 gproj(Dd / 64, (Bb * Ll) / 64);     // (8, 256)

  gemm_nn<<<gproj, 256, 0, stream>>>(Q, WQ, qs,  Bb * Ll, Dd, Dd);
  gemm_nn<<<gproj, 256, 0, stream>>>(K, WK, ks_, Bb * Ll, Dd, Dd);
  gemm_nn<<<gproj, 256, 0, stream>>>(V, WV, vs,  Bb * Ll, Dd, Dd);
  zero_mv<<<64, 256, 0, stream>>>(mv);
  corr_diag<<<dim3(Ll / 64, Ll / 64, Bb), 256, 0, stream>>>(qs, ks_, mv);
  topk_softmax<<<1, 1024, 0, stream>>>(mv, idx, w);
  aggregate<<<dim3(Ll, Bb), 128, 0, stream>>>(vs, w, idx, ctx);
  gemm_nn<<<gproj, 256, 0, stream>>>(ctx, Wfc, out, Bb * Ll, Dd, Dd);
}

// Round 2
// 205.668 us; speedup vs baseline: 5.3584x; 5.3584x over previous
//
#include <hip/hip_runtime.h>
#include <math.h>

namespace {

constexpr int Bb = 16;
constexpr int Ll = 1024;
constexpr int Dd = 512;
constexpr int TOPK = 6;

typedef short  short8 __attribute__((ext_vector_type(8)));
typedef float  f32x4  __attribute__((ext_vector_type(4)));

__device__ __forceinline__ short f2bf(float x) {
  unsigned u = __builtin_bit_cast(unsigned, x);
  u += 0x7fffu + ((u >> 16) & 1u);          // RNE
  return (short)(u >> 16);
}
__device__ __forceinline__ float bf2f(short b) {
  unsigned u = ((unsigned)(unsigned short)b) << 16;
  return __builtin_bit_cast(float, u);
}
__device__ __forceinline__ void g2l16(const void* g, void* l) {
  __builtin_amdgcn_global_load_lds(
      (const __attribute__((address_space(1))) unsigned*)g,
      (__attribute__((address_space(3))) unsigned*)l, 16, 0, 0);
}

// ---------------------------------------------------------------------------
// NT bf16 MFMA GEMM, m97 structure: 128x128 tile, BK=32, 4 waves (2x2 of 64x64),
// 4x4 16x16x32 fragments per wave, global_load_lds width-16 staging.
//   C[m][n] = sum_k A[m][k] * BT[n][k]
// EPI: 0 = store bf16 C, 1 = store fp32 C, 2 = circular-diagonal reduce into
//      mv[bz][ (m - n) mod 1024 ]  (A,BT batch-offset by blockIdx.z)
// ---------------------------------------------------------------------------
template<int EPI>
__global__ __launch_bounds__(256) void gemm_nt(
    const short* __restrict__ A, const short* __restrict__ BT,
    void* __restrict__ Cout, int Mb, int N, int K)
{
  __shared__ short As[128 * 32];
  __shared__ short Bs[128 * 32];
  __shared__ float bins[256];

  const int tid = threadIdx.x;
  const int bz  = blockIdx.z;
  const int m0  = blockIdx.y * 128;
  const int n0  = blockIdx.x * 128;
  const short* Ab = A  + (size_t)bz * Mb * K;
  const short* Bp = BT + (size_t)bz * N  * K;

  // staging map: call c covers rows c*64 + tid/4, col-start (tid&3)*8
  const int srow = tid >> 2;
  const int scol = (tid & 3) * 8;
  const short* ga0 = Ab + (size_t)(m0 + srow) * K + scol;
  const short* ga1 = Ab + (size_t)(m0 + 64 + srow) * K + scol;
  const short* gb0 = Bp + (size_t)(n0 + srow) * K + scol;
  const short* gb1 = Bp + (size_t)(n0 + 64 + srow) * K + scol;
  short* la0 = As + tid * 8;
  short* la1 = As + 2048 + tid * 8;
  short* lb0 = Bs + tid * 8;
  short* lb1 = Bs + 2048 + tid * 8;

  const int lane = tid & 63;
  const int wave = tid >> 6;
  const int wr = wave >> 1, wc = wave & 1;
  const int lo = lane & 15, hi = lane >> 4;

  if (EPI == 2) bins[tid] = 0.f;

  f32x4 acc[4][4];
#pragma unroll
  for (int i = 0; i < 4; ++i)
#pragma unroll
    for (int j = 0; j < 4; ++j) acc[i][j] = (f32x4){0.f, 0.f, 0.f, 0.f};

  for (int k0 = 0; k0 < K; k0 += 32) {
    g2l16(ga0 + k0, la0);
    g2l16(ga1 + k0, la1);
    g2l16(gb0 + k0, lb0);
    g2l16(gb1 + k0, lb1);
    __syncthreads();   // compiler drains vmcnt before barrier

    short8 af[4], bfr[4];
#pragma unroll
    for (int i = 0; i < 4; ++i)
      af[i] = *(const short8*)&As[(wr * 64 + i * 16 + lo) * 32 + hi * 8];
#pragma unroll
    for (int j = 0; j < 4; ++j)
      bfr[j] = *(const short8*)&Bs[(wc * 64 + j * 16 + lo) * 32 + hi * 8];
#pragma unroll
    for (int i = 0; i < 4; ++i)
#pragma unroll
      for (int j = 0; j < 4; ++j)
        acc[i][j] = __builtin_amdgcn_mfma_f32_16x16x32_bf16(af[i], bfr[j], acc[i][j], 0, 0, 0);
    __syncthreads();
  }

  if (EPI == 0) {
    short* C = (short*)Cout;
#pragma unroll
    for (int i = 0; i < 4; ++i)
#pragma unroll
      for (int r = 0; r < 4; ++r) {
        const size_t row = m0 + wr * 64 + i * 16 + hi * 4 + r;
#pragma unroll
        for (int j = 0; j < 4; ++j)
          C[row * N + n0 + wc * 64 + j * 16 + lo] = f2bf(acc[i][j][r]);
      }
  } else if (EPI == 1) {
    float* C = (float*)Cout;
#pragma unroll
    for (int i = 0; i < 4; ++i)
#pragma unroll
      for (int r = 0; r < 4; ++r) {
        const size_t row = m0 + wr * 64 + i * 16 + hi * 4 + r;
#pragma unroll
        for (int j = 0; j < 4; ++j)
          C[row * N + n0 + wc * 64 + j * 16 + lo] = acc[i][j][r];
      }
  } else {
    // register pre-reduce: d = (wr-wc)*64 + 16*(i-j) + 4*hi + r - lo; group by (i-j, r)
    float red[7][4];
#pragma unroll
    for (int d = 0; d < 7; ++d)
#pragma unroll
      for (int r = 0; r < 4; ++r) red[d][r] = 0.f;
#pragma unroll
    for (int i = 0; i < 4; ++i)
#pragma unroll
      for (int j = 0; j < 4; ++j)
#pragma unroll
        for (int r = 0; r < 4; ++r) red[i - j + 3][r] += acc[i][j][r];

    const int dbase = 127 + (wr - wc) * 64 + 4 * hi - lo;
#pragma unroll
    for (int d = 0; d < 7; ++d)
#pragma unroll
      for (int r = 0; r < 4; ++r)
        atomicAdd(&bins[dbase + 16 * (d - 3) + r], red[d][r]);
    __syncthreads();
    if (tid < 255) {
      float* mv = (float*)Cout;
      const int l = (m0 - n0 + tid - 127) & (Ll - 1);
      atomicAdd(&mv[bz * Ll + l], bins[tid]);
    }
  }
}

// fp32 -> bf16 convert, 8 elems/thread
__global__ __launch_bounds__(256) void cvt_bf16(
    const float* __restrict__ in, short* __restrict__ out, int n8)
{
  int i = blockIdx.x * 256 + threadIdx.x;
  if (i >= n8) return;
  const float4 v0 = ((const float4*)in)[i * 2];
  const float4 v1 = ((const float4*)in)[i * 2 + 1];
  short8 o;
  o[0] = f2bf(v0.x); o[1] = f2bf(v0.y); o[2] = f2bf(v0.z); o[3] = f2bf(v0.w);
  o[4] = f2bf(v1.x); o[5] = f2bf(v1.y); o[6] = f2bf(v1.z); o[7] = f2bf(v1.w);
  *(short8*)&out[i * 8] = o;
}

// W[512][512] fp32 -> WT[512][512] bf16 with WT[n][k] = W[k][n]; z picks weight
__global__ __launch_bounds__(256) void wtrans(
    const float* __restrict__ w0, const float* __restrict__ w1,
    const float* __restrict__ w2, const float* __restrict__ w3,
    short* __restrict__ o0, short* __restrict__ o1,
    short* __restrict__ o2, short* __restrict__ o3)
{
  const int z = blockIdx.z;
  const float* W = (z == 0) ? w0 : (z == 1) ? w1 : (z == 2) ? w2 : w3;
  short* O = (z == 0) ? o0 : (z == 1) ? o1 : (z == 2) ? o2 : o3;
  __shared__ float t[32][33];
  const int tx = threadIdx.x & 31, ty = threadIdx.x >> 5;   // 32 x 8
  const int bx = blockIdx.x, by = blockIdx.y;
#pragma unroll
  for (int s = 0; s < 32; s += 8)
    t[ty + s][tx] = W[(size_t)(by * 32 + ty + s) * 512 + bx * 32 + tx];
  __syncthreads();
#pragma unroll
  for (int s = 0; s < 32; s += 8)
    O[(size_t)(bx * 32 + ty + s) * 512 + by * 32 + tx] = f2bf(t[tx][ty + s]);
}

__global__ void zero_mv(float* __restrict__ mv)
{
  int i = blockIdx.x * 256 + threadIdx.x;
  if (i < Bb * Ll) mv[i] = 0.f;
}

__global__ __launch_bounds__(1024) void topk_softmax(
    const float* __restrict__ mean_value,
    int* __restrict__ idx_out, float* __restrict__ w_out)
{
  __shared__ float vals[1024];
  __shared__ int   inds[1024];
  __shared__ float bm[1024];
  __shared__ int   topi[TOPK];
  const int t = threadIdx.x;
  float s = 0.f;
  for (int b = 0; b < Bb; ++b) s += mean_value[b * Ll + t];
  bm[t] = s;
  __syncthreads();
  for (int k = 0; k < TOPK; ++k) {
    bool taken = false;
    for (int j = 0; j < k; ++j) taken |= (topi[j] == t);
    vals[t] = taken ? -INFINITY : bm[t];
    inds[t] = t;
    __syncthreads();
    for (int stride = 512; stride > 0; stride >>= 1) {
      if (t < stride) {
        if (vals[t + stride] > vals[t]) { vals[t] = vals[t + stride]; inds[t] = inds[t + stride]; }
      }
      __syncthreads();
    }
    if (t == 0) topi[k] = inds[0];
    __syncthreads();
  }
  if (t < TOPK) idx_out[t] = topi[t];
  if (t < Bb) {
    float wv[TOPK], mx = -INFINITY;
#pragma unroll
    for (int k = 0; k < TOPK; ++k) {
      wv[k] = mean_value[t * Ll + topi[k]] * (1.f / 512.f);
      mx = fmaxf(mx, wv[k]);
    }
    float sum = 0.f;
#pragma unroll
    for (int k = 0; k < TOPK; ++k) { wv[k] = expf(wv[k] - mx); sum += wv[k]; }
#pragma unroll
    for (int k = 0; k < TOPK; ++k) w_out[t * TOPK + k] = wv[k] / sum;
  }
}

// ctx[b][l][c] = sum_k w[b][k] * vs[b][(l+idx_k)%L][c]   (bf16 in/out, fp32 accum)
__global__ __launch_bounds__(256) void aggregate(
    const short* __restrict__ vs, const float* __restrict__ w,
    const int* __restrict__ idx, short* __restrict__ ctx)
{
  const int b = blockIdx.y;
  __shared__ float ww[8];
  __shared__ int   ii[8];
  if (threadIdx.x < TOPK) { ww[threadIdx.x] = w[b * TOPK + threadIdx.x]; ii[threadIdx.x] = idx[threadIdx.x]; }
  __syncthreads();
  const int l = blockIdx.x * 4 + (threadIdx.x >> 6);
  const int c = (threadIdx.x & 63) * 8;
  const short* vb = vs + (size_t)b * Ll * Dd;
  float a[8] = {};
#pragma unroll
  for (int k = 0; k < TOPK; ++k) {
    const short8 vv = *(const short8*)&vb[(size_t)((l + ii[k]) & (Ll - 1)) * Dd + c];
    const float wk = ww[k];
#pragma unroll
    for (int e = 0; e < 8; ++e) a[e] = fmaf(wk, bf2f(vv[e]), a[e]);
  }
  short8 o;
#pragma unroll
  for (int e = 0; e < 8; ++e) o[e] = f2bf(a[e]);
  *(short8*)&ctx[((size_t)b * Ll + l) * Dd + c] = o;
}

}  // namespace

extern "C" void kernel_launch(void* const* d_in, const int* in_sizes, int n_in,
                              void* d_out, int out_size, void* d_ws, size_t ws_size,
                              hipStream_t stream)
{
  const float* Q   = (const float*)d_in[0];
  const float* K   = (const float*)d_in[1];
  const float* V   = (const float*)d_in[2];
  const float* WQ  = (const float*)d_in[4];
  const float* WK  = (const float*)d_in[5];
  const float* WV  = (const float*)d_in[6];
  const float* Wfc = (const float*)d_in[7];
  float* out = (float*)d_out;

  char* ws = (char*)d_ws;
  const size_t SB = (size_t)Bb * Ll * Dd * sizeof(short);   // 16 MiB per bf16 tensor
  short* inbf = (short*)(ws);
  short* qsb  = (short*)(ws + 1 * SB);
  short* ksb  = (short*)(ws + 2 * SB);
  short* vsb  = (short*)(ws + 3 * SB);
  short* ctxb = (short*)(ws + 4 * SB);
  short* wtq  = (short*)(ws + 5 * SB);
  short* wtk  = wtq + 512 * 512;
  short* wtv  = wtk + 512 * 512;
  short* wtf  = wtv + 512 * 512;
  float* mv   = (float*)(wtf + 512 * 512);
  float* w    = mv + Bb * Ll;
  int*   idx  = (int*)(w + 128);

  const int n8 = Bb * Ll * Dd / 8;                 // 1,048,576
  const dim3 gproj(Dd / 128, (Bb * Ll) / 128, 1);  // (4, 128)

  wtrans<<<dim3(16, 16, 4), 256, 0, stream>>>(WQ, WK, WV, Wfc, wtq, wtk, wtv, wtf);

  cvt_bf16<<<n8 / 256, 256, 0, stream>>>(Q, inbf, n8);
  gemm_nt<0><<<gproj, 256, 0, stream>>>(inbf, wtq, qsb, Bb * Ll, Dd, Dd);
  cvt_bf16<<<n8 / 256, 256, 0, stream>>>(K, inbf, n8);
  gemm_nt<0><<<gproj, 256, 0, stream>>>(inbf, wtk, ksb, Bb * Ll, Dd, Dd);
  cvt_bf16<<<n8 / 256, 256, 0, stream>>>(V, inbf, n8);
  gemm_nt<0><<<gproj, 256, 0, stream>>>(inbf, wtv, vsb, Bb * Ll, Dd, Dd);

  zero_mv<<<64, 256, 0, stream>>>(mv);
  gemm_nt<2><<<dim3(Ll / 128, Ll / 128, Bb), 256, 0, stream>>>(qsb, ksb, mv, Ll, Ll, Dd);
  topk_softmax<<<1, 1024, 0, stream>>>(mv, idx, w);
  aggregate<<<dim3(Ll / 4, Bb), 256, 0, stream>>>(vsb, w, idx, ctxb);
  gemm_nt<1><<<gproj, 256, 0, stream>>>(ctxb, wtf, out, Bb * Ll, Dd, Dd);
}

// Round 3
// 160.590 us; speedup vs baseline: 6.8625x; 1.2807x over previous
//
#include <hip/hip_runtime.h>
#include <math.h>

namespace {

constexpr int Bb = 16;
constexpr int Ll = 1024;
constexpr int Dd = 512;
constexpr int TOPK = 6;

typedef short  short8 __attribute__((ext_vector_type(8)));
typedef float  f32x4  __attribute__((ext_vector_type(4)));

__device__ __forceinline__ short f2bf(float x) {
  unsigned u = __builtin_bit_cast(unsigned, x);
  u += 0x7fffu + ((u >> 16) & 1u);          // RNE
  return (short)(u >> 16);
}
__device__ __forceinline__ float bf2f(short b) {
  unsigned u = ((unsigned)(unsigned short)b) << 16;
  return __builtin_bit_cast(float, u);
}
__device__ __forceinline__ void g2l16(const void* g, void* l) {
  __builtin_amdgcn_global_load_lds(
      (const __attribute__((address_space(1))) unsigned*)g,
      (__attribute__((address_space(3))) unsigned*)l, 16, 0, 0);
}
__device__ __forceinline__ short8 cvt8(float4 a, float4 b) {
  short8 o;
  o[0] = f2bf(a.x); o[1] = f2bf(a.y); o[2] = f2bf(a.z); o[3] = f2bf(a.w);
  o[4] = f2bf(b.x); o[5] = f2bf(b.y); o[6] = f2bf(b.z); o[7] = f2bf(b.w);
  return o;
}

// ===========================================================================
// Projections: C[z] = bf16( fp32A[z] @ WT[z]^T ), z in {Q,K,V}. M=16384,N=K=512.
// 128x128 tile, BK=32, 2-phase prefetch dbuf. A: fp32 reg-stage + cvt (T14
// issue-early/write-late). B: global_load_lds. XCD-swizzled block id.
// ===========================================================================
__global__ __launch_bounds__(256) void proj_gemm(
    const float* __restrict__ Qf, const float* __restrict__ Kf,
    const float* __restrict__ Vf,
    const short* __restrict__ wq, const short* __restrict__ wk,
    const short* __restrict__ wv,
    short* __restrict__ oq, short* __restrict__ ok, short* __restrict__ ov)
{
  constexpr int N = 512, K = 512;
  __shared__ short As[2][4096];
  __shared__ short Bs[2][4096];

  const int z = blockIdx.z;
  const float* Af = (z == 0) ? Qf : (z == 1) ? Kf : Vf;
  const short* Bp = (z == 0) ? wq : (z == 1) ? wk : wv;
  short*       C  = (z == 0) ? oq : (z == 1) ? ok : ov;

  // XCD swizzle: 512 blocks/slice, XCD gets 64 consecutive work ids
  const int f  = blockIdx.x + 4 * blockIdx.y;
  const int s  = (f & 7) * 64 + (f >> 3);
  const int n0 = (s & 3) * 128;
  const int m0 = (s >> 2) * 128;

  const int tid  = threadIdx.x;
  const int srow = tid >> 2;
  const int scol = (tid & 3) * 8;
  const float* fa0 = Af + (size_t)(m0 + srow) * K + scol;
  const float* fa1 = fa0 + (size_t)64 * K;
  const short* gb0 = Bp + (size_t)(n0 + srow) * K + scol;
  const short* gb1 = gb0 + (size_t)64 * K;

  const int lane = tid & 63;
  const int wave = tid >> 6;
  const int wr = wave >> 1, wc = wave & 1;
  const int lo = lane & 15, hi = lane >> 4;

  f32x4 acc[4][4];
#pragma unroll
  for (int i = 0; i < 4; ++i)
#pragma unroll
    for (int j = 0; j < 4; ++j) acc[i][j] = (f32x4){0.f, 0.f, 0.f, 0.f};

  float4 ra0, ra1, ra2, ra3;
#define AISSUE(k) do { \
    ra0 = *(const float4*)(fa0 + (k));     ra1 = *(const float4*)(fa0 + (k) + 4); \
    ra2 = *(const float4*)(fa1 + (k));     ra3 = *(const float4*)(fa1 + (k) + 4); } while (0)
#define AWRITE(buf) do { \
    *(short8*)&As[buf][tid * 8]        = cvt8(ra0, ra1); \
    *(short8*)&As[buf][2048 + tid * 8] = cvt8(ra2, ra3); } while (0)
#define BISSUE(buf, k) do { \
    g2l16(gb0 + (k), &Bs[buf][tid * 8]); \
    g2l16(gb1 + (k), &Bs[buf][2048 + tid * 8]); } while (0)

  AISSUE(0); BISSUE(0, 0); AWRITE(0);
  __syncthreads();

  int cur = 0;
  for (int k0 = 0; k0 < K; k0 += 32) {
    const bool more = (k0 + 32 < K);
    if (more) { AISSUE(k0 + 32); BISSUE(cur ^ 1, k0 + 32); }
    short8 af[4], bfr[4];
#pragma unroll
    for (int i = 0; i < 4; ++i)
      af[i] = *(const short8*)&As[cur][(wr * 64 + i * 16 + lo) * 32 + hi * 8];
#pragma unroll
    for (int j = 0; j < 4; ++j)
      bfr[j] = *(const short8*)&Bs[cur][(wc * 64 + j * 16 + lo) * 32 + hi * 8];
#pragma unroll
    for (int i = 0; i < 4; ++i)
#pragma unroll
      for (int j = 0; j < 4; ++j)
        acc[i][j] = __builtin_amdgcn_mfma_f32_16x16x32_bf16(af[i], bfr[j], acc[i][j], 0, 0, 0);
    if (more) AWRITE(cur ^ 1);    // T14: dependent cvt+ds_write after MFMA
    __syncthreads();
    cur ^= 1;
  }
#undef AISSUE
#undef AWRITE
#undef BISSUE

#pragma unroll
  for (int i = 0; i < 4; ++i)
#pragma unroll
    for (int r = 0; r < 4; ++r) {
      const size_t row = m0 + wr * 64 + i * 16 + hi * 4 + r;
#pragma unroll
      for (int j = 0; j < 4; ++j)
        C[row * N + n0 + wc * 64 + j * 16 + lo] = f2bf(acc[i][j][r]);
    }
}

// ===========================================================================
// Correlation Gram with fused circular-diagonal reduction. Per batch z:
// mv[z][(m-n)%1024] += q_s[m,:]·k_s[n,:].  A,B bf16 via global_load_lds,
// 2-phase prefetch dbuf, XCD swizzle.
// ===========================================================================
__global__ __launch_bounds__(256) void corr_gemm(
    const short* __restrict__ A, const short* __restrict__ BT,
    float* __restrict__ mv)
{
  constexpr int K = 512;
  __shared__ short As[2][4096];
  __shared__ short Bs[2][4096];
  __shared__ float bins[256];

  const int bz = blockIdx.z;
  const int f  = blockIdx.x + 8 * blockIdx.y;     // 64 blocks per batch slice
  const int s  = (f & 7) * 8 + (f >> 3);
  const int n0 = (s & 7) * 128;
  const int m0 = (s >> 3) * 128;
  const short* Ab = A  + (size_t)bz * Ll * K;
  const short* Bp = BT + (size_t)bz * Ll * K;

  const int tid  = threadIdx.x;
  const int srow = tid >> 2;
  const int scol = (tid & 3) * 8;
  const short* ga0 = Ab + (size_t)(m0 + srow) * K + scol;
  const short* ga1 = ga0 + (size_t)64 * K;
  const short* gb0 = Bp + (size_t)(n0 + srow) * K + scol;
  const short* gb1 = gb0 + (size_t)64 * K;

  const int lane = tid & 63;
  const int wave = tid >> 6;
  const int wr = wave >> 1, wc = wave & 1;
  const int lo = lane & 15, hi = lane >> 4;

  bins[tid] = 0.f;

  f32x4 acc[4][4];
#pragma unroll
  for (int i = 0; i < 4; ++i)
#pragma unroll
    for (int j = 0; j < 4; ++j) acc[i][j] = (f32x4){0.f, 0.f, 0.f, 0.f};

#define STAGE(buf, k) do { \
    g2l16(ga0 + (k), &As[buf][tid * 8]); \
    g2l16(ga1 + (k), &As[buf][2048 + tid * 8]); \
    g2l16(gb0 + (k), &Bs[buf][tid * 8]); \
    g2l16(gb1 + (k), &Bs[buf][2048 + tid * 8]); } while (0)

  STAGE(0, 0);
  __syncthreads();

  int cur = 0;
  for (int k0 = 0; k0 < K; k0 += 32) {
    if (k0 + 32 < K) STAGE(cur ^ 1, k0 + 32);
    short8 af[4], bfr[4];
#pragma unroll
    for (int i = 0; i < 4; ++i)
      af[i] = *(const short8*)&As[cur][(wr * 64 + i * 16 + lo) * 32 + hi * 8];
#pragma unroll
    for (int j = 0; j < 4; ++j)
      bfr[j] = *(const short8*)&Bs[cur][(wc * 64 + j * 16 + lo) * 32 + hi * 8];
#pragma unroll
    for (int i = 0; i < 4; ++i)
#pragma unroll
      for (int j = 0; j < 4; ++j)
        acc[i][j] = __builtin_amdgcn_mfma_f32_16x16x32_bf16(af[i], bfr[j], acc[i][j], 0, 0, 0);
    __syncthreads();
    cur ^= 1;
  }
#undef STAGE

  // register pre-reduce over frag diagonals, then LDS bins, then 255 atomics
  float red[7][4];
#pragma unroll
  for (int d = 0; d < 7; ++d)
#pragma unroll
    for (int r = 0; r < 4; ++r) red[d][r] = 0.f;
#pragma unroll
  for (int i = 0; i < 4; ++i)
#pragma unroll
    for (int j = 0; j < 4; ++j)
#pragma unroll
      for (int r = 0; r < 4; ++r) red[i - j + 3][r] += acc[i][j][r];

  const int dbase = 127 + (wr - wc) * 64 + 4 * hi - lo;
#pragma unroll
  for (int d = 0; d < 7; ++d)
#pragma unroll
    for (int r = 0; r < 4; ++r)
      atomicAdd(&bins[dbase + 16 * (d - 3) + r], red[d][r]);
  __syncthreads();
  if (tid < 255) {
    const int l = (m0 - n0 + tid - 127) & (Ll - 1);
    atomicAdd(&mv[bz * Ll + l], bins[tid]);
  }
}

// ===========================================================================
// Final FC: out = fp32( ctx_bf16 @ Wfc^T ). Same structure, bf16 A via
// global_load_lds, fp32 store.
// ===========================================================================
__global__ __launch_bounds__(256) void fc_gemm(
    const short* __restrict__ A, const short* __restrict__ BT,
    float* __restrict__ C)
{
  constexpr int N = 512, K = 512;
  __shared__ short As[2][4096];
  __shared__ short Bs[2][4096];

  const int f  = blockIdx.x + 4 * blockIdx.y;
  const int s  = (f & 7) * 64 + (f >> 3);
  const int n0 = (s & 3) * 128;
  const int m0 = (s >> 2) * 128;

  const int tid  = threadIdx.x;
  const int srow = tid >> 2;
  const int scol = (tid & 3) * 8;
  const short* ga0 = A + (size_t)(m0 + srow) * K + scol;
  const short* ga1 = ga0 + (size_t)64 * K;
  const short* gb0 = BT + (size_t)(n0 + srow) * K + scol;
  const short* gb1 = gb0 + (size_t)64 * K;

  const int lane = tid & 63;
  const int wave = tid >> 6;
  const int wr = wave >> 1, wc = wave & 1;
  const int lo = lane & 15, hi = lane >> 4;

  f32x4 acc[4][4];
#pragma unroll
  for (int i = 0; i < 4; ++i)
#pragma unroll
    for (int j = 0; j < 4; ++j) acc[i][j] = (f32x4){0.f, 0.f, 0.f, 0.f};

#define STAGE(buf, k) do { \
    g2l16(ga0 + (k), &As[buf][tid * 8]); \
    g2l16(ga1 + (k), &As[buf][2048 + tid * 8]); \
    g2l16(gb0 + (k), &Bs[buf][tid * 8]); \
    g2l16(gb1 + (k), &Bs[buf][2048 + tid * 8]); } while (0)

  STAGE(0, 0);
  __syncthreads();

  int cur = 0;
  for (int k0 = 0; k0 < K; k0 += 32) {
    if (k0 + 32 < K) STAGE(cur ^ 1, k0 + 32);
    short8 af[4], bfr[4];
#pragma unroll
    for (int i = 0; i < 4; ++i)
      af[i] = *(const short8*)&As[cur][(wr * 64 + i * 16 + lo) * 32 + hi * 8];
#pragma unroll
    for (int j = 0; j < 4; ++j)
      bfr[j] = *(const short8*)&Bs[cur][(wc * 64 + j * 16 + lo) * 32 + hi * 8];
#pragma unroll
    for (int i = 0; i < 4; ++i)
#pragma unroll
      for (int j = 0; j < 4; ++j)
        acc[i][j] = __builtin_amdgcn_mfma_f32_16x16x32_bf16(af[i], bfr[j], acc[i][j], 0, 0, 0);
    __syncthreads();
    cur ^= 1;
  }
#undef STAGE

#pragma unroll
  for (int i = 0; i < 4; ++i)
#pragma unroll
    for (int r = 0; r < 4; ++r) {
      const size_t row = m0 + wr * 64 + i * 16 + hi * 4 + r;
#pragma unroll
      for (int j = 0; j < 4; ++j)
        C[row * N + n0 + wc * 64 + j * 16 + lo] = acc[i][j][r];
    }
}

// W[512][512] fp32 -> WT bf16 (transposed); z selects which weight
__global__ __launch_bounds__(256) void wtrans(
    const float* __restrict__ w0, const float* __restrict__ w1,
    const float* __restrict__ w2, const float* __restrict__ w3,
    short* __restrict__ o0, short* __restrict__ o1,
    short* __restrict__ o2, short* __restrict__ o3)
{
  const int z = blockIdx.z;
  const float* W = (z == 0) ? w0 : (z == 1) ? w1 : (z == 2) ? w2 : w3;
  short* O = (z == 0) ? o0 : (z == 1) ? o1 : (z == 2) ? o2 : o3;
  __shared__ float t[32][33];
  const int tx = threadIdx.x & 31, ty = threadIdx.x >> 5;
  const int bx = blockIdx.x, by = blockIdx.y;
#pragma unroll
  for (int s = 0; s < 32; s += 8)
    t[ty + s][tx] = W[(size_t)(by * 32 + ty + s) * 512 + bx * 32 + tx];
  __syncthreads();
#pragma unroll
  for (int s = 0; s < 32; s += 8)
    O[(size_t)(bx * 32 + ty + s) * 512 + by * 32 + tx] = f2bf(t[tx][ty + s]);
}

__global__ void zero_mv(float* __restrict__ mv)
{
  int i = blockIdx.x * 256 + threadIdx.x;
  if (i < Bb * Ll) mv[i] = 0.f;
}

__global__ __launch_bounds__(1024) void topk_softmax(
    const float* __restrict__ mean_value,
    int* __restrict__ idx_out, float* __restrict__ w_out)
{
  __shared__ float vals[1024];
  __shared__ int   inds[1024];
  __shared__ float bm[1024];
  __shared__ int   topi[TOPK];
  const int t = threadIdx.x;
  float s = 0.f;
  for (int b = 0; b < Bb; ++b) s += mean_value[b * Ll + t];
  bm[t] = s;
  __syncthreads();
  for (int k = 0; k < TOPK; ++k) {
    bool taken = false;
    for (int j = 0; j < k; ++j) taken |= (topi[j] == t);
    vals[t] = taken ? -INFINITY : bm[t];
    inds[t] = t;
    __syncthreads();
    for (int stride = 512; stride > 0; stride >>= 1) {
      if (t < stride) {
        if (vals[t + stride] > vals[t]) { vals[t] = vals[t + stride]; inds[t] = inds[t + stride]; }
      }
      __syncthreads();
    }
    if (t == 0) topi[k] = inds[0];
    __syncthreads();
  }
  if (t < TOPK) idx_out[t] = topi[t];
  if (t < Bb) {
    float wv[TOPK], mx = -INFINITY;
#pragma unroll
    for (int k = 0; k < TOPK; ++k) {
      wv[k] = mean_value[t * Ll + topi[k]] * (1.f / 512.f);
      mx = fmaxf(mx, wv[k]);
    }
    float sum = 0.f;
#pragma unroll
    for (int k = 0; k < TOPK; ++k) { wv[k] = expf(wv[k] - mx); sum += wv[k]; }
#pragma unroll
    for (int k = 0; k < TOPK; ++k) w_out[t * TOPK + k] = wv[k] / sum;
  }
}

// ctx[b][l][c] = sum_k w[b][k] * vs[b][(l+idx_k)%L][c]   (bf16 in/out, fp32 accum)
__global__ __launch_bounds__(256) void aggregate(
    const short* __restrict__ vs, const float* __restrict__ w,
    const int* __restrict__ idx, short* __restrict__ ctx)
{
  const int b = blockIdx.y;
  __shared__ float ww[8];
  __shared__ int   ii[8];
  if (threadIdx.x < TOPK) { ww[threadIdx.x] = w[b * TOPK + threadIdx.x]; ii[threadIdx.x] = idx[threadIdx.x]; }
  __syncthreads();
  const int l = blockIdx.x * 4 + (threadIdx.x >> 6);
  const int c = (threadIdx.x & 63) * 8;
  const short* vb = vs + (size_t)b * Ll * Dd;
  float a[8] = {};
#pragma unroll
  for (int k = 0; k < TOPK; ++k) {
    const short8 vv = *(const short8*)&vb[(size_t)((l + ii[k]) & (Ll - 1)) * Dd + c];
    const float wk = ww[k];
#pragma unroll
    for (int e = 0; e < 8; ++e) a[e] = fmaf(wk, bf2f(vv[e]), a[e]);
  }
  short8 o;
#pragma unroll
  for (int e = 0; e < 8; ++e) o[e] = f2bf(a[e]);
  *(short8*)&ctx[((size_t)b * Ll + l) * Dd + c] = o;
}

}  // namespace

extern "C" void kernel_launch(void* const* d_in, const int* in_sizes, int n_in,
                              void* d_out, int out_size, void* d_ws, size_t ws_size,
                              hipStream_t stream)
{
  const float* Q   = (const float*)d_in[0];
  const float* K   = (const float*)d_in[1];
  const float* V   = (const float*)d_in[2];
  const float* WQ  = (const float*)d_in[4];
  const float* WK  = (const float*)d_in[5];
  const float* WV  = (const float*)d_in[6];
  const float* Wfc = (const float*)d_in[7];
  float* out = (float*)d_out;

  char* ws = (char*)d_ws;
  const size_t SB = (size_t)Bb * Ll * Dd * sizeof(short);   // 16 MiB per bf16 tensor
  short* qsb  = (short*)(ws);
  short* ksb  = (short*)(ws + 1 * SB);
  short* vsb  = (short*)(ws + 2 * SB);
  short* ctxb = (short*)(ws + 3 * SB);
  short* wtq  = (short*)(ws + 4 * SB);
  short* wtk  = wtq + 512 * 512;
  short* wtv  = wtk + 512 * 512;
  short* wtf  = wtv + 512 * 512;
  float* mv   = (float*)(wtf + 512 * 512);
  float* w    = mv + Bb * Ll;
  int*   idx  = (int*)(w + 128);

  wtrans<<<dim3(16, 16, 4), 256, 0, stream>>>(WQ, WK, WV, Wfc, wtq, wtk, wtv, wtf);
  zero_mv<<<64, 256, 0, stream>>>(mv);

  proj_gemm<<<dim3(4, 128, 3), 256, 0, stream>>>(Q, K, V, wtq, wtk, wtv, qsb, ksb, vsb);
  corr_gemm<<<dim3(8, 8, 16), 256, 0, stream>>>(qsb, ksb, mv);
  topk_softmax<<<1, 1024, 0, stream>>>(mv, idx, w);
  aggregate<<<dim3(Ll / 4, Bb), 256, 0, stream>>>(vsb, w, idx, ctxb);
  fc_gemm<<<dim3(4, 128, 1), 256, 0, stream>>>(ctxb, wtf, out);
}

// Round 4
// 158.977 us; speedup vs baseline: 6.9321x; 1.0102x over previous
//
#include <hip/hip_runtime.h>
#include <math.h>

namespace {

constexpr int Bb = 16;
constexpr int Ll = 1024;
constexpr int Dd = 512;
constexpr int TOPK = 6;
constexpr int Kc = 512;          // K dim of every GEMM
constexpr int NT = Kc / 32;      // 16 K-tiles of BK=32

typedef short  short8 __attribute__((ext_vector_type(8)));
typedef float  f32x4  __attribute__((ext_vector_type(4)));

__device__ __forceinline__ short f2bf(float x) {
  unsigned u = __builtin_bit_cast(unsigned, x);
  u += 0x7fffu + ((u >> 16) & 1u);          // RNE
  return (short)(u >> 16);
}
__device__ __forceinline__ float bf2f(short b) {
  unsigned u = ((unsigned)(unsigned short)b) << 16;
  return __builtin_bit_cast(float, u);
}
__device__ __forceinline__ void g2l16(const void* g, void* l) {
  __builtin_amdgcn_global_load_lds(
      (const __attribute__((address_space(1))) unsigned*)g,
      (__attribute__((address_space(3))) unsigned*)l, 16, 0, 0);
}
__device__ __forceinline__ short8 cvt8(float4 a, float4 b) {
  short8 o;
  o[0] = f2bf(a.x); o[1] = f2bf(a.y); o[2] = f2bf(a.z); o[3] = f2bf(a.w);
  o[4] = f2bf(b.x); o[5] = f2bf(b.y); o[6] = f2bf(b.z); o[7] = f2bf(b.w);
  return o;
}

#define BARRIER() do { asm volatile("" ::: "memory"); \
    __builtin_amdgcn_s_barrier(); \
    asm volatile("" ::: "memory"); } while (0)
#define VMCNT3() asm volatile("s_waitcnt vmcnt(3)" ::: "memory")
#define VMCNT1() asm volatile("s_waitcnt vmcnt(1)" ::: "memory")
#define VMCNT0() asm volatile("s_waitcnt vmcnt(0)" ::: "memory")
#define LGKM0()  do { asm volatile("s_waitcnt lgkmcnt(0)" ::: "memory"); \
    __builtin_amdgcn_sched_barrier(0); } while (0)

// ===========================================================================
// Ring-pipelined NT GEMM: C[m][n] = sum_k A[m][k]*BT[n][k].
// BM=256 BN=128 BK=32; 8 waves (4M x 2N) of 64x64; 3-slot LDS ring; counted
// vmcnt (T3/T4); XOR-swizzled LDS (T2-style, 2-way max); setprio (T5).
// MODE 0: proj (A fp32 reg-staged+cvt, C bf16, z in {Q,K,V})
// MODE 1: corr (A,B bf16; fused circular-diagonal reduce into mv[z]; z=batch)
// MODE 2: fc   (A,B bf16; C fp32)
// LDS slot: A 256x32 bf16 (16KB, 1024 16B-units), B 128x32 bf16 (8KB).
// Swizzle: data (row,c8) stored at unit row*4 + (c8 ^ ((row>>1)&3)).
// ===========================================================================
template<int MODE>
__global__ __launch_bounds__(512) void gemm_ring(
    const void* __restrict__ Aq, const void* __restrict__ Ak,
    const void* __restrict__ Av,
    const short* __restrict__ Bq, const short* __restrict__ Bk,
    const short* __restrict__ Bv,
    void* __restrict__ Cq, void* __restrict__ Ck, void* __restrict__ Cv)
{
  __shared__ short lds3[3][12288];       // per slot: A[0..8191], B[8192..12287]
  __shared__ float bins[384];

  const int tid = threadIdx.x;
  const int z   = blockIdx.z;

  // ---- block tile coords (bijective XCD swizzle; blocks/slice % 8 == 0) ----
  int m0, n0;
  if (MODE == 1) {
    const int fb = blockIdx.x;                 // 32 blocks per batch
    const int s  = (fb & 7) * 4 + (fb >> 3);
    m0 = (s >> 3) * 256;  n0 = (s & 7) * 128;  // 4 x 8 tiles
  } else {
    const int fb = blockIdx.x;                 // 256 blocks per slice
    const int s  = (fb & 7) * 32 + (fb >> 3);
    m0 = (s >> 2) * 256;  n0 = (s & 3) * 128;  // 64 x 4 tiles
  }

  // ---- operand base pointers ----
  const float* Af = nullptr;                   // proj fp32 A
  const short* Ab = nullptr;                   // bf16 A
  const short* Bp;
  if (MODE == 0) {
    Af = (const float*)((z == 0) ? Aq : (z == 1) ? Ak : Av);
    Bp = (z == 0) ? Bq : (z == 1) ? Bk : Bv;
  } else if (MODE == 1) {
    Ab = (const short*)Aq + (size_t)z * Ll * Kc;
    Bp = Bq + (size_t)z * Ll * Kc;
  } else {
    Ab = (const short*)Aq;
    Bp = Bq;
  }

  // ---- staging maps ----
  // B: thread t covers unit u=t: row=t>>2, sl=t&3, src c8 = sl ^ ((row>>1)&3)
  const int rB  = tid >> 2;
  const int c8B = (tid & 3) ^ ((rB >> 1) & 3);
  const short* gB = Bp + (size_t)(n0 + rB) * Kc + c8B * 8;
  const int destB = 8192 + tid * 8;            // short offset in slot

  // A (bf16 modes): units u0=tid (rows 0..127), u1=tid+512 (rows 128..255)
  const int rA  = tid >> 2;
  const int c8A = (tid & 3) ^ ((rA >> 1) & 3); // same swz for rA and rA+128
  const short* gA0 = nullptr; const short* gA1 = nullptr;
  if (MODE != 0) {
    gA0 = Ab + (size_t)(m0 + rA) * Kc + c8A * 8;
    gA1 = gA0 + (size_t)128 * Kc;
  }
  const int destA0 = tid * 8, destA1 = tid * 8 + 4096;

  // A (proj fp32): thread t covers data (row=t>>1, c8 in {2*(t&1), 2*(t&1)+1})
  const int rP  = tid >> 1;
  const int c8P = 2 * (tid & 1);
  const float* gAf = nullptr;
  int uW0 = 0, uW1 = 0;
  if (MODE == 0) {
    gAf = Af + (size_t)(m0 + rP) * Kc + c8P * 8;
    uW0 = rP * 4 + (c8P ^ ((rP >> 1) & 3));
    uW1 = uW0 ^ 1;
  }

  // ---- fragment read offsets (short index in slot, constant per thread) ----
  const int lane = tid & 63;
  const int wid  = tid >> 6;
  const int wr = wid >> 1, wn = wid & 1;
  const int lo = lane & 15, hi = lane >> 4;
  int aoff[4], boff[4];
#pragma unroll
  for (int i = 0; i < 4; ++i) {
    const int ar = wr * 64 + i * 16 + lo;
    aoff[i] = (ar * 4 + (hi ^ ((ar >> 1) & 3))) * 8;
  }
#pragma unroll
  for (int j = 0; j < 4; ++j) {
    const int br = wn * 64 + j * 16 + lo;
    boff[j] = 8192 + (br * 4 + (hi ^ ((br >> 1) & 3))) * 8;
  }

  if (MODE == 1 && tid < 384) bins[tid] = 0.f;

  f32x4 acc[4][4];
#pragma unroll
  for (int i = 0; i < 4; ++i)
#pragma unroll
    for (int j = 0; j < 4; ++j) acc[i][j] = (f32x4){0.f, 0.f, 0.f, 0.f};

  // ---- prologue: stage tiles 0 -> slot0, 1 -> slot1 ----
  if (MODE == 0) {
    float4 p0 = *(const float4*)(gAf + 0);
    float4 p1 = *(const float4*)(gAf + 4);
    float4 p2 = *(const float4*)(gAf + 8);
    float4 p3 = *(const float4*)(gAf + 12);
    g2l16(gB, &lds3[0][destB]);
    float4 q0 = *(const float4*)(gAf + 32);
    float4 q1 = *(const float4*)(gAf + 36);
    float4 q2 = *(const float4*)(gAf + 40);
    float4 q3 = *(const float4*)(gAf + 44);
    g2l16(gB + 32, &lds3[1][destB]);
    *(short8*)&lds3[0][uW0 * 8] = cvt8(p0, p1);
    *(short8*)&lds3[0][uW1 * 8] = cvt8(p2, p3);
    *(short8*)&lds3[1][uW0 * 8] = cvt8(q0, q1);
    *(short8*)&lds3[1][uW1 * 8] = cvt8(q2, q3);
    LGKM0();
    VMCNT1();
  } else {
    g2l16(gA0,      &lds3[0][destA0]);
    g2l16(gA1,      &lds3[0][destA1]);
    g2l16(gB,       &lds3[0][destB]);
    g2l16(gA0 + 32, &lds3[1][destA0]);
    g2l16(gA1 + 32, &lds3[1][destA1]);
    g2l16(gB  + 32, &lds3[1][destB]);
    VMCNT3();
  }
  BARRIER();

  // ---- main 16-phase pipeline ----
  int sr = 0, sw = 2;
#pragma unroll 1
  for (int t = 0; t < NT; ++t) {
    const short* L = &lds3[sr][0];
    short8 af[4], bfr[4];
#pragma unroll
    for (int i = 0; i < 4; ++i) af[i]  = *(const short8*)(L + aoff[i]);
#pragma unroll
    for (int j = 0; j < 4; ++j) bfr[j] = *(const short8*)(L + boff[j]);

    float4 s0, s1, s2, s3;
    if (t < NT - 2) {
      const int ke = (t + 2) * 32;
      if (MODE == 0) {
        s0 = *(const float4*)(gAf + ke + 0);
        s1 = *(const float4*)(gAf + ke + 4);
        s2 = *(const float4*)(gAf + ke + 8);
        s3 = *(const float4*)(gAf + ke + 12);
        g2l16(gB + ke, &lds3[sw][destB]);
      } else {
        g2l16(gA0 + ke, &lds3[sw][destA0]);
        g2l16(gA1 + ke, &lds3[sw][destA1]);
        g2l16(gB  + ke, &lds3[sw][destB]);
      }
    }

    BARRIER();
    __builtin_amdgcn_s_setprio(1);
#pragma unroll
    for (int i = 0; i < 4; ++i)
#pragma unroll
      for (int j = 0; j < 4; ++j)
        acc[i][j] = __builtin_amdgcn_mfma_f32_16x16x32_bf16(af[i], bfr[j], acc[i][j], 0, 0, 0);
    __builtin_amdgcn_s_setprio(0);

    if (MODE == 0) {
      if (t < NT - 2) {
        *(short8*)&lds3[sw][uW0 * 8] = cvt8(s0, s1);
        *(short8*)&lds3[sw][uW1 * 8] = cvt8(s2, s3);
        LGKM0();
        VMCNT1();
      } else if (t == NT - 2) {
        VMCNT0();
      }
    } else {
      if (t < NT - 2)       VMCNT3();
      else if (t == NT - 2) VMCNT0();
    }
    BARRIER();
    sr = (sr == 2) ? 0 : sr + 1;
    sw = (sw == 2) ? 0 : sw + 1;
  }

  // ---- epilogue ----
  if (MODE == 0) {
    short* C = (short*)((z == 0) ? Cq : (z == 1) ? Ck : Cv);
#pragma unroll
    for (int i = 0; i < 4; ++i)
#pragma unroll
      for (int r = 0; r < 4; ++r) {
        const size_t row = m0 + wr * 64 + i * 16 + hi * 4 + r;
#pragma unroll
        for (int j = 0; j < 4; ++j)
          C[row * Dd + n0 + wn * 64 + j * 16 + lo] = f2bf(acc[i][j][r]);
      }
  } else if (MODE == 2) {
    float* C = (float*)Cq;
#pragma unroll
    for (int i = 0; i < 4; ++i)
#pragma unroll
      for (int r = 0; r < 4; ++r) {
        const size_t row = m0 + wr * 64 + i * 16 + hi * 4 + r;
#pragma unroll
        for (int j = 0; j < 4; ++j)
          C[row * Dd + n0 + wn * 64 + j * 16 + lo] = acc[i][j][r];
      }
  } else {
    // circular-diagonal reduce: d = (m - n); register pre-reduce by (i-j, r)
    float red[7][4];
#pragma unroll
    for (int d = 0; d < 7; ++d)
#pragma unroll
      for (int r = 0; r < 4; ++r) red[d][r] = 0.f;
#pragma unroll
    for (int i = 0; i < 4; ++i)
#pragma unroll
      for (int j = 0; j < 4; ++j)
#pragma unroll
        for (int r = 0; r < 4; ++r) red[i - j + 3][r] += acc[i][j][r];

    const int dbase = 127 + (wr * 64 - wn * 64) + 4 * hi - lo;
#pragma unroll
    for (int d = 0; d < 7; ++d)
#pragma unroll
      for (int r = 0; r < 4; ++r)
        atomicAdd(&bins[dbase + 16 * (d - 3) + r], red[d][r]);
    __syncthreads();
    if (tid < 383) {
      float* mv = (float*)Cq;
      const int l = (m0 - n0 + tid - 127) & (Ll - 1);
      atomicAdd(&mv[z * Ll + l], bins[tid]);
    }
  }
}

// W[512][512] fp32 -> WT bf16 (transposed); z selects which weight
__global__ __launch_bounds__(256) void wtrans(
    const float* __restrict__ w0, const float* __restrict__ w1,
    const float* __restrict__ w2, const float* __restrict__ w3,
    short* __restrict__ o0, short* __restrict__ o1,
    short* __restrict__ o2, short* __restrict__ o3)
{
  const int z = blockIdx.z;
  const float* W = (z == 0) ? w0 : (z == 1) ? w1 : (z == 2) ? w2 : w3;
  short* O = (z == 0) ? o0 : (z == 1) ? o1 : (z == 2) ? o2 : o3;
  __shared__ float t[32][33];
  const int tx = threadIdx.x & 31, ty = threadIdx.x >> 5;
  const int bx = blockIdx.x, by = blockIdx.y;
#pragma unroll
  for (int s = 0; s < 32; s += 8)
    t[ty + s][tx] = W[(size_t)(by * 32 + ty + s) * 512 + bx * 32 + tx];
  __syncthreads();
#pragma unroll
  for (int s = 0; s < 32; s += 8)
    O[(size_t)(bx * 32 + ty + s) * 512 + by * 32 + tx] = f2bf(t[tx][ty + s]);
}

__global__ void zero_mv(float* __restrict__ mv)
{
  int i = blockIdx.x * 256 + threadIdx.x;
  if (i < Bb * Ll) mv[i] = 0.f;
}

__global__ __launch_bounds__(1024) void topk_softmax(
    const float* __restrict__ mean_value,
    int* __restrict__ idx_out, float* __restrict__ w_out)
{
  __shared__ float vals[1024];
  __shared__ int   inds[1024];
  __shared__ float bm[1024];
  __shared__ int   topi[TOPK];
  const int t = threadIdx.x;
  float s = 0.f;
  for (int b = 0; b < Bb; ++b) s += mean_value[b * Ll + t];
  bm[t] = s;
  __syncthreads();
  for (int k = 0; k < TOPK; ++k) {
    bool taken = false;
    for (int j = 0; j < k; ++j) taken |= (topi[j] == t);
    vals[t] = taken ? -INFINITY : bm[t];
    inds[t] = t;
    __syncthreads();
    for (int stride = 512; stride > 0; stride >>= 1) {
      if (t < stride) {
        if (vals[t + stride] > vals[t]) { vals[t] = vals[t + stride]; inds[t] = inds[t + stride]; }
      }
      __syncthreads();
    }
    if (t == 0) topi[k] = inds[0];
    __syncthreads();
  }
  if (t < TOPK) idx_out[t] = topi[t];
  if (t < Bb) {
    float wv[TOPK], mx = -INFINITY;
#pragma unroll
    for (int k = 0; k < TOPK; ++k) {
      wv[k] = mean_value[t * Ll + topi[k]] * (1.f / 512.f);
      mx = fmaxf(mx, wv[k]);
    }
    float sum = 0.f;
#pragma unroll
    for (int k = 0; k < TOPK; ++k) { wv[k] = expf(wv[k] - mx); sum += wv[k]; }
#pragma unroll
    for (int k = 0; k < TOPK; ++k) w_out[t * TOPK + k] = wv[k] / sum;
  }
}

// ctx[b][l][c] = sum_k w[b][k] * vs[b][(l+idx_k)%L][c]   (bf16 in/out, fp32 accum)
__global__ __launch_bounds__(256) void aggregate(
    const short* __restrict__ vs, const float* __restrict__ w,
    const int* __restrict__ idx, short* __restrict__ ctx)
{
  const int b = blockIdx.y;
  __shared__ float ww[8];
  __shared__ int   ii[8];
  if (threadIdx.x < TOPK) { ww[threadIdx.x] = w[b * TOPK + threadIdx.x]; ii[threadIdx.x] = idx[threadIdx.x]; }
  __syncthreads();
  const int l = blockIdx.x * 4 + (threadIdx.x >> 6);
  const int c = (threadIdx.x & 63) * 8;
  const short* vb = vs + (size_t)b * Ll * Dd;
  float a[8] = {};
#pragma unroll
  for (int k = 0; k < TOPK; ++k) {
    const short8 vv = *(const short8*)&vb[(size_t)((l + ii[k]) & (Ll - 1)) * Dd + c];
    const float wk = ww[k];
#pragma unroll
    for (int e = 0; e < 8; ++e) a[e] = fmaf(wk, bf2f(vv[e]), a[e]);
  }
  short8 o;
#pragma unroll
  for (int e = 0; e < 8; ++e) o[e] = f2bf(a[e]);
  *(short8*)&ctx[((size_t)b * Ll + l) * Dd + c] = o;
}

}  // namespace

extern "C" void kernel_launch(void* const* d_in, const int* in_sizes, int n_in,
                              void* d_out, int out_size, void* d_ws, size_t ws_size,
                              hipStream_t stream)
{
  const float* Q   = (const float*)d_in[0];
  const float* K   = (const float*)d_in[1];
  const float* V   = (const float*)d_in[2];
  const float* WQ  = (const float*)d_in[4];
  const float* WK  = (const float*)d_in[5];
  const float* WV  = (const float*)d_in[6];
  const float* Wfc = (const float*)d_in[7];
  float* out = (float*)d_out;

  char* ws = (char*)d_ws;
  const size_t SB = (size_t)Bb * Ll * Dd * sizeof(short);   // 16 MiB per bf16 tensor
  short* qsb  = (short*)(ws);
  short* ksb  = (short*)(ws + 1 * SB);
  short* vsb  = (short*)(ws + 2 * SB);
  short* ctxb = (short*)(ws + 3 * SB);
  short* wtq  = (short*)(ws + 4 * SB);
  short* wtk  = wtq + 512 * 512;
  short* wtv  = wtk + 512 * 512;
  short* wtf  = wtv + 512 * 512;
  float* mv   = (float*)(wtf + 512 * 512);
  float* w    = mv + Bb * Ll;
  int*   idx  = (int*)(w + 128);

  wtrans<<<dim3(16, 16, 4), 256, 0, stream>>>(WQ, WK, WV, Wfc, wtq, wtk, wtv, wtf);
  zero_mv<<<64, 256, 0, stream>>>(mv);

  gemm_ring<0><<<dim3(256, 1, 3), 512, 0, stream>>>(
      Q, K, V, wtq, wtk, wtv, qsb, ksb, vsb);
  gemm_ring<1><<<dim3(32, 1, 16), 512, 0, stream>>>(
      qsb, nullptr, nullptr, ksb, nullptr, nullptr, mv, nullptr, nullptr);
  topk_softmax<<<1, 1024, 0, stream>>>(mv, idx, w);
  aggregate<<<dim3(Ll / 4, Bb), 256, 0, stream>>>(vsb, w, idx, ctxb);
  gemm_ring<2><<<dim3(256, 1, 1), 512, 0, stream>>>(
      ctxb, nullptr, nullptr, wtf, nullptr, nullptr, out, nullptr, nullptr);
}